// Round 16
// baseline (123.957 us; speedup 1.0000x reference)
//
#include <hip/hip_runtime.h>
#include <stdint.h>
#include <math.h>

#define NSEQ   2048
#define VV     64
#define HID    512
#define LMAX   64
#define MINLEN 4
#define H_ROWS 4226   // 65*65 (parent,sib) rows + 1 row for t==0
#define H_T0   4225

// ---------------- threefry2x32 (JAX/Random123, 20 rounds; KAT-verified) ----
__device__ __forceinline__ uint32_t rotl32(uint32_t x, int r) {
  return (x << r) | (x >> (32 - r));
}
__device__ __forceinline__ void threefry2x32(uint32_t ks0, uint32_t ks1,
                                             uint32_t x0, uint32_t x1,
                                             uint32_t &o0, uint32_t &o1) {
  uint32_t ks2 = ks0 ^ ks1 ^ 0x1BD11BDAu;
  x0 += ks0; x1 += ks1;
#define TF_RND(r) { x0 += x1; x1 = rotl32(x1, (r)); x1 ^= x0; }
  TF_RND(13) TF_RND(15) TF_RND(26) TF_RND(6)
  x0 += ks1; x1 += ks2 + 1u;
  TF_RND(17) TF_RND(29) TF_RND(16) TF_RND(24)
  x0 += ks2; x1 += ks0 + 2u;
  TF_RND(13) TF_RND(15) TF_RND(26) TF_RND(6)
  x0 += ks0; x1 += ks1 + 3u;
  TF_RND(17) TF_RND(29) TF_RND(16) TF_RND(24)
  x0 += ks1; x1 += ks2 + 4u;
  TF_RND(13) TF_RND(15) TF_RND(26) TF_RND(6)
  x0 += ks2; x1 += ks0 + 5u;
#undef TF_RND
  o0 = x0; o1 = x1;
}

// gumbel from the (verified) partitionable bit recipe
__device__ __forceinline__ float gumbel_bits(uint32_t k0, uint32_t k1,
                                             uint32_t idx) {
  uint32_t b0, b1;
  threefry2x32(k0, k1, 0u, idx, b0, b1);
  const uint32_t bits = b0 ^ b1;
  const float f = __uint_as_float((bits >> 9) | 0x3f800000u) - 1.0f;
  const float u = (f == 0.f) ? 1.17549435e-38f : f;
  return -logf(-logf(u));
}

// ---------------- DPP wave reductions (no DS ops) ----------------
template <int CTRL>
__device__ __forceinline__ float dppf(float v) {
  return __int_as_float(__builtin_amdgcn_update_dpp(
      __float_as_int(v), __float_as_int(v), CTRL, 0xF, 0xF, false));
}
__device__ __forceinline__ float wave_max_bcast(float v) {
  v = fmaxf(v, dppf<0x121>(v));
  v = fmaxf(v, dppf<0x122>(v));
  v = fmaxf(v, dppf<0x124>(v));
  v = fmaxf(v, dppf<0x128>(v));
  v = fmaxf(v, dppf<0x142>(v));
  v = fmaxf(v, dppf<0x143>(v));
  return __int_as_float(__builtin_amdgcn_readlane(__float_as_int(v), 63));
}
__device__ __forceinline__ float wave_sum_bcast(float v) {
  v += dppf<0x121>(v);
  v += dppf<0x122>(v);
  v += dppf<0x124>(v);
  v += dppf<0x128>(v);
  v += dppf<0x142>(v);
  v += dppf<0x143>(v);
  return __int_as_float(__builtin_amdgcn_readlane(__float_as_int(v), 63));
}

// ---- precompute: hconst, xw0 (f64 acc) + per-step threefry keys ktab ----
__global__ void rnn_precompute(const float *__restrict__ input_init,
                               const float *__restrict__ hidden_init,
                               const float *__restrict__ Wx,
                               const float *__restrict__ Wh,
                               const float *__restrict__ b,
                               float *__restrict__ hconst,
                               float *__restrict__ xw0,
                               uint32_t *__restrict__ ktab) {
  const int k = blockIdx.x * 64 + threadIdx.x;
  if (blockIdx.x == 0) {
    const int t = threadIdx.x;   // 64 threads = 64 steps
    uint32_t o0, o1;
    threefry2x32(0u, 1234u, 0u, (uint32_t)t, o0, o1);
    ktab[2 * t]     = o0;
    ktab[2 * t + 1] = o1;
  }
  if (k >= HID) return;
  double acc = 0.0;
  for (int j = 0; j < HID; ++j)
    acc = fma((double)hidden_init[j], (double)Wh[(size_t)j * HID + k], acc);
  hconst[k] = (float)(acc + (double)b[k]);
  double a2 = 0.0;
  for (int j = 0; j < 2 * VV; ++j)
    a2 = fma((double)input_init[j], (double)Wx[(size_t)j * HID + k], a2);
  xw0[k] = (float)a2;
}

// ---- X table: row r -> logits x[v] = H[r]·Wp[:,v] + bp[v] ----
// Early-exits rows whose parent is not an operator (provably unreachable).
__global__ __launch_bounds__(512) void rnn_xtable(
    const float *__restrict__ Wx, const float *__restrict__ Wp,
    const float *__restrict__ bp,
    const float *__restrict__ hconst, const float *__restrict__ xw0,
    const int *__restrict__ two_arr, int n2,
    const int *__restrict__ one_arr, int n1,
    float *__restrict__ X) {
  __shared__ float  smh[HID];
  __shared__ double smpart[8][VV];

  const int r   = blockIdx.x;
  const int tid = threadIdx.x;

  if (r != H_T0) {
    const int p = r / 65 - 1;
    if (p >= 0) {
      bool isOp = false;
      for (int j = 0; j < n2; ++j) isOp |= (p == two_arr[j]);
      for (int j = 0; j < n1; ++j) isOp |= (p == one_arr[j]);
      if (!isOp) return;          // unreachable row
    }
  }

  {
    float ax;
    if (r == H_T0) {
      ax = xw0[tid];
    } else {
      const int p = r / 65 - 1;
      const int s = r % 65 - 1;
      ax = 0.f;
      if (p >= 0) ax = Wx[(size_t)p * HID + tid];
      if (s >= 0) ax += Wx[(size_t)(VV + s) * HID + tid];
    }
    smh[tid] = tanhf(ax + hconst[tid]);
  }
  __syncthreads();

  const int v  = tid & 63;
  const int sl = tid >> 6;
  double acc = 0.0;
  for (int k = sl * 64; k < sl * 64 + 64; ++k)
    acc = fma((double)smh[k], (double)Wp[(size_t)k * VV + v], acc);
  smpart[sl][v] = acc;
  __syncthreads();

  if (tid < VV) {
    double s = 0.0;
#pragma unroll
    for (int i = 0; i < 8; ++i) s += smpart[i][tid];
    X[(size_t)r * VV + tid] = (float)(s + (double)bp[tid]);
  }
}

// ---- gumbel table (f32) at full occupancy: 1 threefry + 2 logf per elem ----
__global__ __launch_bounds__(256) void rnn_gumbel_table(
    const uint32_t *__restrict__ ktab, float *__restrict__ g) {
  const int t   = blockIdx.y;
  const int idx = blockIdx.x * 256 + threadIdx.x;   // < NSEQ*VV
  g[(size_t)t * (NSEQ * VV) + idx] =
      gumbel_bits(ktab[2 * t], ktab[2 * t + 1], (uint32_t)idx);
}

// --------- main sampler: 1 wave = 1 seq, zero LDS, zero DS ops -----
__global__ __launch_bounds__(64) void rnn_sampler(
    const float *__restrict__ Wx, const float *__restrict__ Wp,
    const float *__restrict__ bp,
    const float *__restrict__ hconst_g, const float *__restrict__ xw0_g,
    const int *__restrict__ two_arr, int n2,
    const int *__restrict__ one_arr, int n1,
    const int *__restrict__ var_arr, int nv,
    const float *__restrict__ Xtab, const float *__restrict__ gtab,
    const uint32_t *__restrict__ ktab, int useX, int useG,
    float *__restrict__ out) {
  const int lane = threadIdx.x;   // = token id v
  const int n    = blockIdx.x;    // sequence id
  const uint32_t idx = (uint32_t)((n << 6) + lane);

  bool isTwo = false, isOne = false, isVar = false;
  for (int j = 0; j < n2; ++j) isTwo |= (lane == two_arr[j]);
  for (int j = 0; j < n1; ++j) isOne |= (lane == one_arr[j]);
  for (int j = 0; j < nv; ++j) isVar |= (lane == var_arr[j]);
  const unsigned long long two_mask = __ballot(isTwo);
  const unsigned long long one_mask = __ballot(isOne);
  const unsigned long long var_mask = __ballot(isVar);
  const bool two_v   = (two_mask >> lane) & 1ull;
  const bool one_v   = (one_mask >> lane) & 1ull;
  const bool zero_v  = !(two_v || one_v);
  const bool const_v = zero_v && !((var_mask >> lane) & 1ull);
  const float bp_v   = bp[lane];

  // fallback-only per-lane slices (k = 64*i + lane)
  float hc[8], xw[8];
  if (!useX) {
#pragma unroll
    for (int i = 0; i < 8; ++i) {
      hc[i] = hconst_g[i * 64 + lane];
      xw[i] = xw0_g[i * 64 + lane];
    }
  }

  int myseq = -1;                 // lane t holds seq[t]
  unsigned long long twoHist = 0ull, oneHist = 0ull;
  int counters = 1;
  bool alive = true, hasvar = false;
  float accE = 0.f, accLP = 0.f;
  int lenacc = 0;
  int row = H_T0;

  float g32 = useG ? gtab[idx] : gumbel_bits(ktab[0], ktab[1], idx);

  for (int t = 0; t < LMAX; ++t) {
    // next-step gumbel: independent, overlaps the dependent X load
    float g_nxt = 0.f;
    if (t + 1 < LMAX)
      g_nxt = useG ? gtab[(size_t)(t + 1) * (NSEQ * VV) + idx]
                   : gumbel_bits(ktab[2 * (t + 1)], ktab[2 * (t + 1) + 1], idx);

    // ---- logits x[lane] for this row
    float x;
    if (useX) {
      x = Xtab[(size_t)row * VV + lane];        // wave-uniform row, L2-hot
    } else {
      float hreg[8];
#pragma unroll
      for (int i = 0; i < 8; ++i) {
        float ax;
        if (row == H_T0) {
          ax = xw[i];
        } else {
          const int p  = row / 65 - 1;
          const int sb = row % 65 - 1;
          ax = 0.f;
          if (p >= 0) ax = Wx[(size_t)p * HID + i * 64 + lane];
          if (sb >= 0) ax += Wx[(size_t)(VV + sb) * HID + i * 64 + lane];
        }
        hreg[i] = (float)tanh((double)(ax + hc[i]));
      }
      float acc = 0.f;
#pragma unroll
      for (int i = 0; i < 8; ++i) {
        for (int j = 0; j < 64; ++j) {
          const float hk = __int_as_float(
              __builtin_amdgcn_readlane(__float_as_int(hreg[i]), j));
          acc = fmaf(hk, Wp[(size_t)(i * 64 + j) * VV + lane], acc);
        }
      }
      x = acc + bp_v;
    }

    // ---- mask + sample: argmax(g + x)  (shift-invariant vs reference)
    const int tot = t + counters;
    bool keep = true;
    if (zero_v && tot < MINLEN) keep = false;
    if (two_v && (tot + 2 > LMAX)) keep = false;
    if (one_v && (tot + 1 > LMAX)) keep = false;
    if (const_v && !hasvar && (counters == 1)) keep = false;

    const float val = keep ? (g32 + x) : -__builtin_inff();
    const float mv  = wave_max_bcast(val);
    const unsigned long long win = __ballot(val == mv);
    const int token = __ffsll((long long)win) - 1;

    const bool tk2 = (two_mask >> token) & 1ull;
    const bool tk1 = (one_mask >> token) & 1ull;
    const bool tkv = (var_mask >> token) & 1ull;

    if (lane == t) myseq = token;
    twoHist = (twoHist << 1) | (unsigned long long)(tk2 ? 1 : 0);
    oneHist = (oneHist << 1) | (unsigned long long)(tk1 ? 1 : 0);

    counters += -1 + 2 * (int)tk2 + (int)tk1;
    const bool aliveN = alive && (counters > 0);

    // ---- stats only while alive (wave-uniform branch; loose tolerance)
    if (alive) {
      const float ex = expf(x);
      const float ek = keep ? ex : 0.f;
      const float s2 = wave_sum_bcast(ek);
      const float dd = wave_sum_bcast(ek * x);
      const float logS2 = logf(s2);
      const int tok_u = __builtin_amdgcn_readfirstlane(token);
      const float x_tok = __int_as_float(
          __builtin_amdgcn_readlane(__float_as_int(x), tok_u));
      if (aliveN) {
        accLP += x_tok - logS2;
        accE  += logS2 - dd / s2;
        lenacc++;
      }
    }
    alive = aliveN;
    hasvar = hasvar || tkv;

    // ---- parent/sibling from scalar arity-history words (no DS ops)
    int parent, sib;
    if (tk2 || tk1) {
      parent = token; sib = -1;
    } else {
      const unsigned long long mle = (2ull << lane) - 1ull;
      const int c = 2 * __popcll(twoHist & mle) + __popcll(oneHist & mle) -
                    (lane + 1);
      const unsigned long long hb = __ballot((lane <= t) && (c == 0));
      if (hb == 0ull) {
        parent = -1; sib = -1;
      } else {
        int kf = __ffsll((long long)hb) - 1;
        kf = __builtin_amdgcn_readfirstlane(kf);
        parent = __builtin_amdgcn_readlane(myseq, t - kf);
        sib = (kf == 0) ? -1 : __builtin_amdgcn_readlane(myseq, t - kf + 1);
      }
    }
    row = (parent + 1) * 65 + (sib + 1);
    g32 = g_nxt;
  }

  // ---- outputs (f32): [seq (2048x64) | lengths | ents | lps]
  out[(size_t)n * LMAX + lane] = (float)myseq;
  if (lane == 0) {
    out[(size_t)NSEQ * LMAX + n]       = (float)(lenacc + 1);
    out[(size_t)NSEQ * (LMAX + 1) + n] = accE;
    out[(size_t)NSEQ * (LMAX + 2) + n] = accLP;
  }
}

extern "C" void kernel_launch(void *const *d_in, const int *in_sizes, int n_in,
                              void *d_out, int out_size, void *d_ws, size_t ws_size,
                              hipStream_t stream) {
  (void)n_in; (void)out_size;
  const float *input_init  = (const float *)d_in[0];
  const float *hidden_init = (const float *)d_in[1];
  const float *Wx = (const float *)d_in[2];
  const float *Wh = (const float *)d_in[3];
  const float *b  = (const float *)d_in[4];
  const float *Wp = (const float *)d_in[5];
  const float *bp = (const float *)d_in[6];
  const int *two_arr = (const int *)d_in[7];
  const int *one_arr = (const int *)d_in[8];
  const int *var_arr = (const int *)d_in[9];
  const int n2 = in_sizes[7], n1 = in_sizes[8], nv = in_sizes[9];

  // ws: [hconst 2KB | xw0 2KB | ktab 512B @4096 | X 1.08MB @8192 | g 33.5MB]
  const size_t offK = 4096;
  const size_t offX = 8192;
  const size_t szX  = (size_t)H_ROWS * VV * sizeof(float);
  const size_t offG = (offX + szX + 255) & ~(size_t)255;
  const size_t szG  = (size_t)LMAX * NSEQ * VV * sizeof(float);
  const int useX = (ws_size >= offX + szX) ? 1 : 0;
  const int useG = (ws_size >= offG + szG) ? 1 : 0;

  float    *hconst = (float *)d_ws;
  float    *xw0    = hconst + HID;
  uint32_t *ktab   = (uint32_t *)((char *)d_ws + offK);
  float    *Xtab   = (float *)((char *)d_ws + offX);
  float    *gtab   = (float *)((char *)d_ws + offG);
  float    *out    = (float *)d_out;

  rnn_precompute<<<8, 64, 0, stream>>>(input_init, hidden_init, Wx, Wh, b,
                                       hconst, xw0, ktab);
  if (useG)
    rnn_gumbel_table<<<dim3((NSEQ * VV) / 256, LMAX), 256, 0, stream>>>(ktab,
                                                                        gtab);
  if (useX)
    rnn_xtable<<<H_ROWS, 512, 0, stream>>>(Wx, Wp, bp, hconst, xw0,
                                           two_arr, n2, one_arr, n1, Xtab);

  rnn_sampler<<<NSEQ, 64, 0, stream>>>(Wx, Wp, bp, hconst, xw0,
                                       two_arr, n2, one_arr, n1,
                                       var_arr, nv, Xtab, gtab, ktab,
                                       useX, useG, out);
}